// Round 2
// baseline (2590.927 us; speedup 1.0000x reference)
//
#include <hip/hip_runtime.h>

#define T_STEPS 23
#define ORD 256
#define HID 512
#define IN_DIM 256
#define NBATCH 8192
#define SLOPE 0.2f
#define LDH (T_STEPS * HID)   // row stride (floats) of out viewed as [b][t][h]
#define ROWS 32               // batch rows per rec block

__device__ __forceinline__ float lrelu(float x) { return x >= 0.f ? x : SLOPE * x; }

// bf16 helpers (round-to-nearest-even, bit tricks; inputs are normal floats)
__device__ __forceinline__ ushort f2bf(float x) {
    unsigned u = __float_as_uint(x);
    u += 0x7fffu + ((u >> 16) & 1u);
    return (ushort)(u >> 16);
}
__device__ __forceinline__ float bf2f(ushort h) { return __uint_as_float((unsigned)h << 16); }

typedef __attribute__((ext_vector_type(8))) short bf16x8;
typedef __attribute__((ext_vector_type(4))) float f32x4;

__device__ __forceinline__ f32x4 nt_load4(const float* p) {
    return __builtin_nontemporal_load((const f32x4*)p);
}
__device__ __forceinline__ void nt_store4(float* p, f32x4 v) {
    __builtin_nontemporal_store(v, (f32x4*)p);
}

// ---------------------------------------------------------------------------
// Kernel 1: V[k][i] = (A^k @ Bv)[i], k = 0..22. One block, 256 threads.
__global__ void vchain_kernel(const float* __restrict__ A,
                              const float* __restrict__ Bv,
                              float* __restrict__ V) {
    __shared__ float v[ORD];
    int i = threadIdx.x;
    v[i] = Bv[i];
    __syncthreads();
    for (int k = 0; k < T_STEPS; ++k) {
        V[k * ORD + i] = v[i];
        float a = 0.f;
        const float4* ar = (const float4*)(A + i * ORD);
        const float4* vr = (const float4*)v;
        #pragma unroll 8
        for (int t = 0; t < ORD / 4; ++t) {
            float4 a4 = ar[t];
            float4 v4 = vr[t];
            a += a4.x * v4.x + a4.y * v4.y + a4.z * v4.z + a4.w * v4.w;
        }
        __syncthreads();
        v[i] = a;
        __syncthreads();
    }
}

// ---------------------------------------------------------------------------
// Kernel 2: wtab[k][j] = sum_i W_m[j][i] * V[k][i].  grid (23, 8), 64 threads.
__global__ void wtab_kernel(const float* __restrict__ Wm,
                            const float* __restrict__ V,
                            float* __restrict__ wtab) {
    __shared__ float vs[ORD];
    int k = blockIdx.x;
    int j = blockIdx.y * 64 + threadIdx.x;
    ((float4*)vs)[threadIdx.x] = ((const float4*)(V + k * ORD))[threadIdx.x];
    __syncthreads();
    float a = 0.f;
    const float4* wr = (const float4*)(Wm + j * ORD);
    const float4* vr = (const float4*)vs;
    #pragma unroll 8
    for (int i = 0; i < ORD / 4; ++i) {
        float4 w4 = wr[i];
        float4 v4 = vr[i];
        a += w4.x * v4.x + w4.y * v4.y + w4.z * v4.z + w4.w * v4.w;
    }
    wtab[k * HID + j] = a;
}

// ---------------------------------------------------------------------------
// Kernel 3: u[r] = dot(X[r, :], e_x), r = b*23 + t over 188416 rows.
__global__ void u_kernel(const float* __restrict__ X,
                         const float* __restrict__ ex,
                         float* __restrict__ u) {
    int row = blockIdx.x * 4 + (threadIdx.x >> 6);
    int lane = threadIdx.x & 63;
    const float4* xp = (const float4*)(X + (size_t)row * IN_DIM);
    const float4* ep = (const float4*)ex;
    float4 x4 = xp[lane];
    float4 e4 = ep[lane];
    float acc = x4.x * e4.x + x4.y * e4.y + x4.z * e4.z + x4.w * e4.w;
    #pragma unroll
    for (int off = 32; off; off >>= 1) acc += __shfl_down(acc, off);
    if (lane == 0) u[row] = acc;
}

// ---------------------------------------------------------------------------
// Kernel 4: C[r][n] = sum_k X[r][k] * Wx[k][n].  M=188416, K=256, N=512.
__global__ __launch_bounds__(256) void gemm_xwx(const float* __restrict__ X,
                                                const float* __restrict__ Wx,
                                                float* __restrict__ out) {
    __shared__ float As[16][68];
    __shared__ float Bs[16][68];
    int tid = threadIdx.x;
    int row0 = blockIdx.x * 64;
    int col0 = blockIdx.y * 64;
    int tx = tid & 15, ty = tid >> 4;
    int am = tid >> 2, ak4 = tid & 3;
    float acc[4][4] = {};
    for (int k0 = 0; k0 < 256; k0 += 16) {
        float4 av = *(const float4*)(X + (size_t)(row0 + am) * IN_DIM + k0 + ak4 * 4);
        float4 bv = *(const float4*)(Wx + (size_t)(k0 + ty) * HID + col0 + tx * 4);
        __syncthreads();
        As[ak4 * 4 + 0][am] = av.x;
        As[ak4 * 4 + 1][am] = av.y;
        As[ak4 * 4 + 2][am] = av.z;
        As[ak4 * 4 + 3][am] = av.w;
        *(float4*)&Bs[ty][tx * 4] = bv;
        __syncthreads();
        #pragma unroll
        for (int kk = 0; kk < 16; ++kk) {
            float4 a4 = *(const float4*)&As[kk][ty * 4];
            float4 b4 = *(const float4*)&Bs[kk][tx * 4];
            float a[4] = {a4.x, a4.y, a4.z, a4.w};
            float b[4] = {b4.x, b4.y, b4.z, b4.w};
            #pragma unroll
            for (int i = 0; i < 4; ++i)
                #pragma unroll
                for (int j = 0; j < 4; ++j)
                    acc[i][j] += a[i] * b[j];
        }
    }
    #pragma unroll
    for (int i = 0; i < 4; ++i) {
        float4 v = make_float4(acc[i][0], acc[i][1], acc[i][2], acc[i][3]);
        *(float4*)(out + (size_t)(row0 + ty * 4 + i) * HID + col0 + tx * 4) = v;
    }
}

// ---------------------------------------------------------------------------
// Kernel 5: out[b][t][j] += sum_{s<=t} u[b][s] * wtab[t-s][j].
__global__ __launch_bounds__(512) void memconv_kernel(const float* __restrict__ u,
                                                      const float* __restrict__ wtab,
                                                      float* __restrict__ out) {
    int b = blockIdx.x, j = threadIdx.x;
    __shared__ float us[T_STEPS];
    if (j < T_STEPS) us[j] = u[b * T_STEPS + j];
    float w[T_STEPS];
    #pragma unroll
    for (int k = 0; k < T_STEPS; ++k) w[k] = wtab[k * HID + j];
    __syncthreads();
    float* ob = out + (size_t)b * LDH + j;
    #pragma unroll
    for (int t = 0; t < T_STEPS; ++t) {
        float acc = 0.f;
        #pragma unroll
        for (int s = 0; s <= t; ++s) acc += us[s] * w[t - s];
        ob[t * HID] += acc;
    }
}

// ---------------------------------------------------------------------------
// Kernel 6: pack Wh (512x512 f32, [n][k]) into bf16 hi/lo arrays laid out
// in A-fragment order for mfma_f32_16x16x32_bf16 with the "swapped" GEMM
// D[n][m] = sum_k Wh[n][k] * h[m][k].
// A-frag layout: lane l, elem e -> row n = f*16 + (l&15),
//                k = s*32 + 4*(l>>4) + (e&3) + 16*(e>>2).
// Storage: whp[((f*16 + s)*64 + l)*8 + e]  (1 KB per fragment block, coalesced).
__global__ void whpack_kernel(const float* __restrict__ Wh,
                              ushort* __restrict__ whi,
                              ushort* __restrict__ wlo) {
    int f = blockIdx.x;        // n-fragment 0..31
    int s = blockIdx.y;        // k-step 0..15
    int l = threadIdx.x;       // lane 0..63
    int n = f * 16 + (l & 15);
    int k0 = s * 32 + 4 * (l >> 4);
    float4 a = *(const float4*)(Wh + (size_t)n * HID + k0);
    float4 b = *(const float4*)(Wh + (size_t)n * HID + k0 + 16);
    float v[8] = {a.x, a.y, a.z, a.w, b.x, b.y, b.z, b.w};
    unsigned hp[4], lp[4];
    #pragma unroll
    for (int e2 = 0; e2 < 4; ++e2) {
        ushort h0 = f2bf(v[2 * e2]),     h1 = f2bf(v[2 * e2 + 1]);
        ushort l0 = f2bf(v[2 * e2]     - bf2f(h0));
        ushort l1 = f2bf(v[2 * e2 + 1] - bf2f(h1));
        hp[e2] = (unsigned)h0 | ((unsigned)h1 << 16);
        lp[e2] = (unsigned)l0 | ((unsigned)l1 << 16);
    }
    size_t off = ((size_t)(f * 16 + s) * 64 + l) * 8;
    *(uint4*)(whi + off) = make_uint4(hp[0], hp[1], hp[2], hp[3]);
    *(uint4*)(wlo + off) = make_uint4(lp[0], lp[1], lp[2], lp[3]);
}

// ---------------------------------------------------------------------------
// Kernel 7: fused recurrence, all 23 timesteps, bf16x3 MFMA.
// Block = 32 batch rows x all 512 cols, 1024 threads (16 waves, 4/SIMD), grid 256.
// Wave w owns n in [w*32, w*32+32): jf in {0,1}; bi in {0,1} (rows bi*16+lm).
// h in LDS as bf16 hi/lo, DOUBLE-BUFFERED (one barrier per t), XOR-swizzled:
//   off(m,k) = m*512 + (k ^ ((m&15)<<2))   (ushort units, 8B-granular)
// Streaming pre/out via nt loads/stores so Wh stays L2-resident.
// pre[t] is prefetched into regs BEFORE the barrier and added in the epilogue.

__device__ __forceinline__ bf16x8 ld_frag(const ushort* base, int o1, int o2) {
    ushort4 p = *(const ushort4*)(base + o1);
    ushort4 q = *(const ushort4*)(base + o2);
    bf16x8 r;
    r[0] = (short)p.x; r[1] = (short)p.y; r[2] = (short)p.z; r[3] = (short)p.w;
    r[4] = (short)q.x; r[5] = (short)q.y; r[6] = (short)q.z; r[7] = (short)q.w;
    return r;
}

__device__ __forceinline__ void store_hilo(ushort* hhi, ushort* hlo, int off, f32x4 v) {
    ushort h0 = f2bf(v[0]), h1 = f2bf(v[1]), h2 = f2bf(v[2]), h3 = f2bf(v[3]);
    *(ushort4*)(hhi + off) = make_ushort4(h0, h1, h2, h3);
    ushort l0 = f2bf(v[0] - bf2f(h0));
    ushort l1 = f2bf(v[1] - bf2f(h1));
    ushort l2 = f2bf(v[2] - bf2f(h2));
    ushort l3 = f2bf(v[3] - bf2f(h3));
    *(ushort4*)(hlo + off) = make_ushort4(l0, l1, l2, l3);
}

__global__ __launch_bounds__(1024) void rec_fused(const ushort* __restrict__ whi,
                                                  const ushort* __restrict__ wlo,
                                                  float* __restrict__ out) {
    __shared__ ushort hbuf[2][2][ROWS * 512];   // [buf][hi/lo][...], 128 KB
    const int tid = threadIdx.x;
    const int w  = tid >> 6;     // wave 0..15
    const int l  = tid & 63;
    const int lm = l & 15;       // m-within-fragment (B col / D col)
    const int g  = l >> 4;       // lane group 0..3
    const int row0 = blockIdx.x * ROWS;
    const int xsw = lm << 2;     // LDS swizzle (ushort units)

    // Fragment (jf, bi) covers rows row0+bi*16+lm, cols w*32+jf*16+4g+{0..3}.
    float* obase[2];
    obase[0] = out + (size_t)(row0 + lm) * LDH + w * 32 + 4 * g;
    obase[1] = out + (size_t)(row0 + 16 + lm) * LDH + w * 32 + 4 * g;

    // ---- t = 0: h_0 = lrelu(pre_0); write back; seed h into buf 0 ----
    #pragma unroll
    for (int bi = 0; bi < 2; ++bi) {
        #pragma unroll
        for (int jf = 0; jf < 2; ++jf) {
            f32x4 vv = nt_load4(obase[bi] + jf * 16);
            vv[0] = lrelu(vv[0]); vv[1] = lrelu(vv[1]);
            vv[2] = lrelu(vv[2]); vv[3] = lrelu(vv[3]);
            nt_store4(obase[bi] + jf * 16, vv);
            int m  = bi * 16 + lm;
            int nb = w * 32 + jf * 16 + 4 * g;
            store_hilo(&hbuf[0][0][0], &hbuf[0][1][0], m * 512 + (nb ^ xsw), vv);
        }
    }

    // Wh-packed per-lane base for this wave (fragments f = w*2 + jf)
    const ushort* wh_l = whi + (size_t)w * 16384 + (size_t)l * 8;
    const ushort* wl_l = wlo + (size_t)w * 16384 + (size_t)l * 8;

    int buf = 0;
    #pragma unroll 1
    for (int t = 1; t < T_STEPS; ++t) {
        // Prefetch pre[t] BEFORE the barrier (independent of h); consume in epilogue.
        f32x4 pregs[2][2];
        #pragma unroll
        for (int jf = 0; jf < 2; ++jf)
            #pragma unroll
            for (int bi = 0; bi < 2; ++bi)
                pregs[jf][bi] = nt_load4(obase[bi] + t * HID + jf * 16);

        __syncthreads();   // h[t-1] in hbuf[buf] visible

        const ushort* hh = &hbuf[buf][0][0];
        const ushort* hl = &hbuf[buf][1][0];
        f32x4 acc[2][2] = {};

        #pragma unroll
        for (int s = 0; s < 16; ++s) {
            bf16x8 ah[2], al[2], bh[2], bl[2];
            #pragma unroll
            for (int jf = 0; jf < 2; ++jf) {
                ah[jf] = *(const bf16x8*)(wh_l + jf * 8192 + s * 512);
                al[jf] = *(const bf16x8*)(wl_l + jf * 8192 + s * 512);
            }
            #pragma unroll
            for (int bi = 0; bi < 2; ++bi) {
                int m  = bi * 16 + lm;
                int o1 = m * 512 + ((s * 32 + 4 * g)      ^ xsw);
                int o2 = m * 512 + ((s * 32 + 16 + 4 * g) ^ xsw);
                bh[bi] = ld_frag(hh, o1, o2);
                bl[bi] = ld_frag(hl, o1, o2);
            }
            #pragma unroll
            for (int jf = 0; jf < 2; ++jf)
                #pragma unroll
                for (int bi = 0; bi < 2; ++bi) {
                    acc[jf][bi] = __builtin_amdgcn_mfma_f32_16x16x32_bf16(ah[jf], bh[bi], acc[jf][bi], 0, 0, 0);
                    acc[jf][bi] = __builtin_amdgcn_mfma_f32_16x16x32_bf16(ah[jf], bl[bi], acc[jf][bi], 0, 0, 0);
                    acc[jf][bi] = __builtin_amdgcn_mfma_f32_16x16x32_bf16(al[jf], bh[bi], acc[jf][bi], 0, 0, 0);
                }
        }

        // No second barrier: writes go to the OTHER buffer; next t's barrier
        // orders them against next t's reads.
        buf ^= 1;
        #pragma unroll
        for (int jf = 0; jf < 2; ++jf)
            #pragma unroll
            for (int bi = 0; bi < 2; ++bi) {
                f32x4 r;
                r[0] = lrelu(acc[jf][bi][0] + pregs[jf][bi][0]);
                r[1] = lrelu(acc[jf][bi][1] + pregs[jf][bi][1]);
                r[2] = lrelu(acc[jf][bi][2] + pregs[jf][bi][2]);
                r[3] = lrelu(acc[jf][bi][3] + pregs[jf][bi][3]);
                nt_store4(obase[bi] + t * HID + jf * 16, r);
                int m  = bi * 16 + lm;
                int nb = w * 32 + jf * 16 + 4 * g;
                store_hilo(&hbuf[buf][0][0], &hbuf[buf][1][0], m * 512 + (nb ^ xsw), r);
            }
    }
}

// ---------------------------------------------------------------------------
extern "C" void kernel_launch(void* const* d_in, const int* in_sizes, int n_in,
                              void* d_out, int out_size, void* d_ws, size_t ws_size,
                              hipStream_t stream) {
    const float* X  = (const float*)d_in[0];  // (8192, 23, 256)
    const float* A  = (const float*)d_in[1];  // (256, 256)
    const float* Bv = (const float*)d_in[2];  // (256, 1)
    const float* Wh = (const float*)d_in[3];  // (512, 512)
    const float* Wm = (const float*)d_in[4];  // (512, 256)
    const float* Wx = (const float*)d_in[5];  // (256, 512)
    const float* ex = (const float*)d_in[6];  // (256, 1)
    float* out = (float*)d_out;               // (8192, 23, 512)

    // workspace: u [188416] f32 | V [23*256] f32 | wtab [23*512] f32 |
    //            whp_hi [512*512] bf16 | whp_lo [512*512] bf16
    float* u    = (float*)d_ws;
    float* V    = u + NBATCH * T_STEPS;
    float* wtab = V + T_STEPS * ORD;
    ushort* whp_hi = (ushort*)(wtab + T_STEPS * HID);
    ushort* whp_lo = whp_hi + HID * HID;

    const int nrows = NBATCH * T_STEPS;  // 188416

    // 1) memory-kernel taps + Wh fragment prepack
    vchain_kernel<<<1, 256, 0, stream>>>(A, Bv, V);
    wtab_kernel<<<dim3(T_STEPS, HID / 64), 64, 0, stream>>>(Wm, V, wtab);
    whpack_kernel<<<dim3(HID / 16, HID / 32), 64, 0, stream>>>(Wh, whp_hi, whp_lo);

    // 2) u = X @ e_x
    u_kernel<<<nrows / 4, 256, 0, stream>>>(X, ex, u);

    // 3) out = X @ W_x (all rows)
    gemm_xwx<<<dim3(nrows / 64, HID / 64), 256, 0, stream>>>(X, Wx, out);

    // 4) out += causal conv of u with wtab
    memconv_kernel<<<NBATCH, HID, 0, stream>>>(u, wtab, out);

    // 5) t = 0..22 fused recurrence, bf16x3 MFMA, one block per 32 batch rows.
    rec_fused<<<NBATCH / ROWS, 1024, 0, stream>>>(whp_hi, whp_lo, out);
}

// Round 4
// 2092.088 us; speedup vs baseline: 1.2384x; 1.2384x over previous
//
#include <hip/hip_runtime.h>

#define T_STEPS 23
#define ORD 256
#define HID 512
#define IN_DIM 256
#define NBATCH 8192
#define SLOPE 0.2f
#define LDH (T_STEPS * HID)   // row stride (floats) of out viewed as [b][t][h]
#define ROWS 32               // batch rows per rec block
#define PRB 64                // rows per gemm_pre block

__device__ __forceinline__ float lrelu(float x) { return x >= 0.f ? x : SLOPE * x; }

// bf16 helpers (round-to-nearest-even)
__device__ __forceinline__ ushort f2bf(float x) {
    unsigned u = __float_as_uint(x);
    u += 0x7fffu + ((u >> 16) & 1u);
    return (ushort)(u >> 16);
}
__device__ __forceinline__ float bf2f(ushort h) { return __uint_as_float((unsigned)h << 16); }

typedef __attribute__((ext_vector_type(8))) short bf16x8;
typedef __attribute__((ext_vector_type(4))) float f32x4;

// Fragment mappings (HW-verified by rounds 1-2 passing):
//   A-frag (lane l, elem e): row n = (l&15), k = 4*(l>>4) + (e&3) + 16*(e>>2)
//   B-frag (lane l, elem e): col m = (l&15), k = same formula
//   C/D   (lane l, reg r):   col m = (l&15), row n = (l>>4)*4 + r

__device__ __forceinline__ bf16x8 ld_frag(const ushort* base, int o1, int o2) {
    ushort4 p = *(const ushort4*)(base + o1);
    ushort4 q = *(const ushort4*)(base + o2);
    bf16x8 r;
    r[0] = (short)p.x; r[1] = (short)p.y; r[2] = (short)p.z; r[3] = (short)p.w;
    r[4] = (short)q.x; r[5] = (short)q.y; r[6] = (short)q.z; r[7] = (short)q.w;
    return r;
}

__device__ __forceinline__ void store_hilo(ushort* hhi, ushort* hlo, int off, f32x4 v) {
    ushort h0 = f2bf(v[0]), h1 = f2bf(v[1]), h2 = f2bf(v[2]), h3 = f2bf(v[3]);
    *(ushort4*)(hhi + off) = make_ushort4(h0, h1, h2, h3);
    ushort l0 = f2bf(v[0] - bf2f(h0));
    ushort l1 = f2bf(v[1] - bf2f(h1));
    ushort l2 = f2bf(v[2] - bf2f(h2));
    ushort l3 = f2bf(v[3] - bf2f(h3));
    *(ushort4*)(hlo + off) = make_ushort4(l0, l1, l2, l3);
}

__device__ __forceinline__ void split_hilo(float x, ushort& hi, ushort& lo) {
    hi = f2bf(x); lo = f2bf(x - bf2f(hi));
}

__device__ __forceinline__ void nt_store4(float* p, f32x4 v) {
    __builtin_nontemporal_store(v, (f32x4*)p);
}

// ---------------------------------------------------------------------------
// Kernel 1: V[k][i] = (A^k @ Bv)[i], k = 0..22. One block, 256 threads.
__global__ void vchain_kernel(const float* __restrict__ A,
                              const float* __restrict__ Bv,
                              float* __restrict__ V) {
    __shared__ float v[ORD];
    int i = threadIdx.x;
    v[i] = Bv[i];
    __syncthreads();
    for (int k = 0; k < T_STEPS; ++k) {
        V[k * ORD + i] = v[i];
        float a = 0.f;
        const float4* ar = (const float4*)(A + i * ORD);
        const float4* vr = (const float4*)v;
        #pragma unroll 8
        for (int t = 0; t < ORD / 4; ++t) {
            float4 a4 = ar[t];
            float4 v4 = vr[t];
            a += a4.x * v4.x + a4.y * v4.y + a4.z * v4.z + a4.w * v4.w;
        }
        __syncthreads();
        v[i] = a;
        __syncthreads();
    }
}

// ---------------------------------------------------------------------------
// Kernel 2: wtab[k][j] = sum_i W_m[j][i] * V[k][i].  grid (23, 8), 64 threads.
__global__ void wtab_kernel(const float* __restrict__ Wm,
                            const float* __restrict__ V,
                            float* __restrict__ wtab) {
    __shared__ float vs[ORD];
    int k = blockIdx.x;
    int j = blockIdx.y * 64 + threadIdx.x;
    ((float4*)vs)[threadIdx.x] = ((const float4*)(V + k * ORD))[threadIdx.x];
    __syncthreads();
    float a = 0.f;
    const float4* wr = (const float4*)(Wm + j * ORD);
    const float4* vr = (const float4*)vs;
    #pragma unroll 8
    for (int i = 0; i < ORD / 4; ++i) {
        float4 w4 = wr[i];
        float4 v4 = vr[i];
        a += w4.x * v4.x + w4.y * v4.y + w4.z * v4.z + w4.w * v4.w;
    }
    wtab[k * HID + j] = a;
}

// ---------------------------------------------------------------------------
// Kernel 3: u[r] = dot(X[r, :], e_x), r = b*23 + t over 188416 rows.
__global__ void u_kernel(const float* __restrict__ X,
                         const float* __restrict__ ex,
                         float* __restrict__ u) {
    int row = blockIdx.x * 4 + (threadIdx.x >> 6);
    int lane = threadIdx.x & 63;
    const float4* xp = (const float4*)(X + (size_t)row * IN_DIM);
    const float4* ep = (const float4*)ex;
    float4 x4 = xp[lane];
    float4 e4 = ep[lane];
    float acc = x4.x * e4.x + x4.y * e4.y + x4.z * e4.z + x4.w * e4.w;
    #pragma unroll
    for (int off = 32; off; off >>= 1) acc += __shfl_down(acc, off);
    if (lane == 0) u[row] = acc;
}

// ---------------------------------------------------------------------------
// Kernel 4: pack Wh (512x512 f32, [n][k]) into A-fragment-ordered bf16 hi/lo.
// Storage: whp[((f*16 + s)*64 + l)*8 + e], f = n/16 (0..31), s = k-step (0..15).
__global__ void whpack_kernel(const float* __restrict__ Wh,
                              ushort* __restrict__ whi,
                              ushort* __restrict__ wlo) {
    int f = blockIdx.x, s = blockIdx.y, l = threadIdx.x;
    int n = f * 16 + (l & 15);
    int k0 = s * 32 + 4 * (l >> 4);
    float4 a = *(const float4*)(Wh + (size_t)n * HID + k0);
    float4 b = *(const float4*)(Wh + (size_t)n * HID + k0 + 16);
    float v[8] = {a.x, a.y, a.z, a.w, b.x, b.y, b.z, b.w};
    unsigned hp[4], lp[4];
    #pragma unroll
    for (int e2 = 0; e2 < 4; ++e2) {
        ushort h0, l0, h1, l1;
        split_hilo(v[2 * e2], h0, l0);
        split_hilo(v[2 * e2 + 1], h1, l1);
        hp[e2] = (unsigned)h0 | ((unsigned)h1 << 16);
        lp[e2] = (unsigned)l0 | ((unsigned)l1 << 16);
    }
    size_t off = ((size_t)(f * 16 + s) * 64 + l) * 8;
    *(uint4*)(whi + off) = make_uint4(hp[0], hp[1], hp[2], hp[3]);
    *(uint4*)(wlo + off) = make_uint4(lp[0], lp[1], lp[2], lp[3]);
}

// ---------------------------------------------------------------------------
// Kernel 5: pack Wx (256x512 f32, [k][n]) into A-fragment order.
// A[n][k] = Wx[k][n]. Storage: wxp[((f*8 + s)*64 + l)*8 + e], s = 0..7.
__global__ void wxpack_kernel(const float* __restrict__ Wx,
                              ushort* __restrict__ whi,
                              ushort* __restrict__ wlo) {
    int f = blockIdx.x, s = blockIdx.y, l = threadIdx.x;
    int n = f * 16 + (l & 15);
    ushort hp[8], lp[8];
    #pragma unroll
    for (int e = 0; e < 8; ++e) {
        int k = s * 32 + 4 * (l >> 4) + (e & 3) + 16 * (e >> 2);
        split_hilo(Wx[(size_t)k * HID + n], hp[e], lp[e]);
    }
    size_t off = ((size_t)(f * 8 + s) * 64 + l) * 8;
    *(uint4*)(whi + off) = *(uint4*)hp;
    *(uint4*)(wlo + off) = *(uint4*)lp;
}

// ---------------------------------------------------------------------------
// Kernel 6: pack wtab (23x512 f32, [k][n]) as ONE A-fragment K-step
// (K padded to 32 with zeros). Storage: wtp[(f*64 + l)*8 + e], f = 0..31.
__global__ void wtabpack_kernel(const float* __restrict__ wtab,
                                ushort* __restrict__ whi,
                                ushort* __restrict__ wlo) {
    int f = blockIdx.x, l = threadIdx.x;
    int n = f * 16 + (l & 15);
    ushort hp[8], lp[8];
    #pragma unroll
    for (int e = 0; e < 8; ++e) {
        int k = 4 * (l >> 4) + (e & 3) + 16 * (e >> 2);
        float v = (k < T_STEPS) ? wtab[(size_t)k * HID + n] : 0.f;
        split_hilo(v, hp[e], lp[e]);
    }
    size_t off = ((size_t)f * 64 + l) * 8;
    *(uint4*)(whi + off) = *(uint4*)hp;
    *(uint4*)(wlo + off) = *(uint4*)lp;
}

// ---------------------------------------------------------------------------
// Kernel 7: pre = X @ Wx + conv(u, wtab), bf16x3 MFMA.  Replaces the old
// gemm_xwx + memconv.  M=188416 (64 rows/block), N=512 (wave w: n in
// [w*64,w*64+64), jf 0..3), K = 256 (s 0..7, X/Wx) + 32 (s=8, Utap/wtab).
// X staged hi/lo in LDS, swizzled off(m,k) = m*256 + (k ^ ((m&15)<<2)).
// Utap fragments built ON THE FLY from u (LDS-staged 86 floats/block):
//   Utap[row][k] = (k<=t) ? u[b][t-k] : 0,  u index = row - k.
__global__ __launch_bounds__(512, 2) void gemm_pre(const float* __restrict__ X,
                                                   const float* __restrict__ u,
                                                   const ushort* __restrict__ wxhi,
                                                   const ushort* __restrict__ wxlo,
                                                   const ushort* __restrict__ wthi,
                                                   const ushort* __restrict__ wtlo,
                                                   float* __restrict__ out) {
    __shared__ ushort xs[2][PRB * 256];   // hi, lo; 64 KB
    __shared__ float us_sh[PRB + 22];     // u[row0-22 .. row0+63]
    const int tid = threadIdx.x;
    const int w = tid >> 6, l = tid & 63, lm = l & 15, g = l >> 4;
    const int row0 = blockIdx.x * PRB;
    const int xsw = lm << 2;

    // ---- stage u slice + X tile (64 rows x 256 k) to LDS as bf16 hi/lo ----
    if (tid < PRB + 22) {
        int idx = row0 - 22 + tid;
        us_sh[tid] = (idx >= 0) ? u[idx] : 0.f;
    }
    {
        int r = tid >> 3;          // 0..63
        int c8 = tid & 7;
        const float4* xrow = (const float4*)(X + (size_t)(row0 + r) * IN_DIM);
        int xswr = (r & 15) << 2;
        #pragma unroll
        for (int i = 0; i < 8; ++i) {
            float4 v4 = xrow[c8 + i * 8];
            f32x4 vv; vv[0] = v4.x; vv[1] = v4.y; vv[2] = v4.z; vv[3] = v4.w;
            int k0 = (c8 + i * 8) * 4;
            store_hilo(&xs[0][0], &xs[1][0], r * 256 + (k0 ^ xswr), vv);
        }
    }
    __syncthreads();

    f32x4 acc[4][4] = {};   // [jf][bi]
    const ushort* wxh_l = wxhi + (size_t)w * 16384 + (size_t)l * 8;
    const ushort* wxl_l = wxlo + (size_t)w * 16384 + (size_t)l * 8;

    #pragma unroll
    for (int s = 0; s < 8; ++s) {
        bf16x8 bh[4], bl[4];
        #pragma unroll
        for (int bi = 0; bi < 4; ++bi) {
            int m = bi * 16 + lm;
            int o1 = m * 256 + ((s * 32 + 4 * g) ^ xsw);
            int o2 = m * 256 + ((s * 32 + 16 + 4 * g) ^ xsw);
            bh[bi] = ld_frag(&xs[0][0], o1, o2);
            bl[bi] = ld_frag(&xs[1][0], o1, o2);
        }
        #pragma unroll
        for (int jf = 0; jf < 4; ++jf) {
            bf16x8 ah = *(const bf16x8*)(wxh_l + jf * 4096 + s * 512);
            bf16x8 al = *(const bf16x8*)(wxl_l + jf * 4096 + s * 512);
            #pragma unroll
            for (int bi = 0; bi < 4; ++bi) {
                acc[jf][bi] = __builtin_amdgcn_mfma_f32_16x16x32_bf16(ah, bh[bi], acc[jf][bi], 0, 0, 0);
                acc[jf][bi] = __builtin_amdgcn_mfma_f32_16x16x32_bf16(ah, bl[bi], acc[jf][bi], 0, 0, 0);
                acc[jf][bi] = __builtin_amdgcn_mfma_f32_16x16x32_bf16(al, bh[bi], acc[jf][bi], 0, 0, 0);
            }
        }
    }

    // ---- s = 8: conv term.  Utap B-frags built from us_sh; wtab A-frags. ----
    {
        bf16x8 bh[4], bl[4];
        #pragma unroll
        for (int bi = 0; bi < 4; ++bi) {
            int rloc = bi * 16 + lm;                 // row - row0
            int t = (row0 + rloc) % T_STEPS;
            #pragma unroll
            for (int e = 0; e < 8; ++e) {
                int k = 4 * g + (e & 3) + 16 * (e >> 2);
                float v = (k <= t) ? us_sh[rloc + 22 - k] : 0.f;
                ushort hi, lo;
                split_hilo(v, hi, lo);
                bh[bi][e] = (short)hi;
                bl[bi][e] = (short)lo;
            }
        }
        #pragma unroll
        for (int jf = 0; jf < 4; ++jf) {
            bf16x8 ah = *(const bf16x8*)(wthi + (size_t)(w * 4 + jf) * 512 + l * 8);
            bf16x8 al = *(const bf16x8*)(wtlo + (size_t)(w * 4 + jf) * 512 + l * 8);
            #pragma unroll
            for (int bi = 0; bi < 4; ++bi) {
                acc[jf][bi] = __builtin_amdgcn_mfma_f32_16x16x32_bf16(ah, bh[bi], acc[jf][bi], 0, 0, 0);
                acc[jf][bi] = __builtin_amdgcn_mfma_f32_16x16x32_bf16(ah, bl[bi], acc[jf][bi], 0, 0, 0);
                acc[jf][bi] = __builtin_amdgcn_mfma_f32_16x16x32_bf16(al, bh[bi], acc[jf][bi], 0, 0, 0);
            }
        }
    }

    // ---- write pre: out viewed as [188416][512] ----
    #pragma unroll
    for (int bi = 0; bi < 4; ++bi) {
        float* op = out + (size_t)(row0 + bi * 16 + lm) * HID + w * 64 + 4 * g;
        #pragma unroll
        for (int jf = 0; jf < 4; ++jf) {
            float4 v = make_float4(acc[jf][bi][0], acc[jf][bi][1], acc[jf][bi][2], acc[jf][bi][3]);
            *(float4*)(op + jf * 16) = v;
        }
    }
}

// ---------------------------------------------------------------------------
// Kernel 8: fused recurrence, all 23 timesteps, bf16x3 MFMA.
// 512 thr (8 waves), wave w owns n in [w*64, w*64+64) (jf 0..3), bi 0..1.
// h double-buffered in LDS (128 KB, one barrier per t), swizzled:
//   off(m,k) = m*512 + (k ^ ((m&15)<<2))   (ushort units)
// pre[t] prefetched into regs BEFORE the barrier; Wh fragment loads software-
// pipelined one s-step ahead.  Plain (cached) loads; NT stores for out-writes
// (write-once stream — keeps L2 clean for Wh residency).
__global__ __launch_bounds__(512, 2) void rec_fused(const ushort* __restrict__ whi,
                                                    const ushort* __restrict__ wlo,
                                                    float* __restrict__ out) {
    __shared__ ushort hbuf[2][2][ROWS * 512];   // [buf][hi/lo], 128 KB
    const int tid = threadIdx.x;
    const int w = tid >> 6, l = tid & 63, lm = l & 15, g = l >> 4;
    const int row0 = blockIdx.x * ROWS;
    const int xsw = lm << 2;

    float* obase[2];
    obase[0] = out + (size_t)(row0 + lm) * LDH + w * 64 + 4 * g;
    obase[1] = out + (size_t)(row0 + 16 + lm) * LDH + w * 64 + 4 * g;

    // ---- t = 0: h_0 = lrelu(pre_0); write back; seed buf 0 ----
    #pragma unroll
    for (int bi = 0; bi < 2; ++bi) {
        #pragma unroll
        for (int jf = 0; jf < 4; ++jf) {
            f32x4 vv = *(f32x4*)(obase[bi] + jf * 16);
            vv[0] = lrelu(vv[0]); vv[1] = lrelu(vv[1]);
            vv[2] = lrelu(vv[2]); vv[3] = lrelu(vv[3]);
            nt_store4(obase[bi] + jf * 16, vv);
            int m = bi * 16 + lm;
            int nb = w * 64 + jf * 16 + 4 * g;
            store_hilo(&hbuf[0][0][0], &hbuf[0][1][0], m * 512 + (nb ^ xsw), vv);
        }
    }

    const ushort* wh_l = whi + (size_t)w * 32768 + (size_t)l * 8;
    const ushort* wl_l = wlo + (size_t)w * 32768 + (size_t)l * 8;

    int buf = 0;
    #pragma unroll 1
    for (int t = 1; t < T_STEPS; ++t) {
        // pre[t] prefetch (independent of h) — consumed in epilogue
        f32x4 pregs[4][2];
        #pragma unroll
        for (int jf = 0; jf < 4; ++jf)
            #pragma unroll
            for (int bi = 0; bi < 2; ++bi)
                pregs[jf][bi] = *(f32x4*)(obase[bi] + t * HID + jf * 16);

        // preload s=0 Wh fragments (h-independent)
        bf16x8 ahc[4], alc[4];
        #pragma unroll
        for (int jf = 0; jf < 4; ++jf) {
            ahc[jf] = *(const bf16x8*)(wh_l + jf * 8192);
            alc[jf] = *(const bf16x8*)(wl_l + jf * 8192);
        }

        __syncthreads();   // h[t-1] in hbuf[buf] visible

        const ushort* hh = &hbuf[buf][0][0];
        const ushort* hl = &hbuf[buf][1][0];
        f32x4 acc[4][2] = {};

        #pragma unroll
        for (int s = 0; s < 16; ++s) {
            bf16x8 ahn[4], aln[4];
            if (s < 15) {
                #pragma unroll
                for (int jf = 0; jf < 4; ++jf) {
                    ahn[jf] = *(const bf16x8*)(wh_l + jf * 8192 + (s + 1) * 512);
                    aln[jf] = *(const bf16x8*)(wl_l + jf * 8192 + (s + 1) * 512);
                }
            }
            bf16x8 bh[2], bl[2];
            #pragma unroll
            for (int bi = 0; bi < 2; ++bi) {
                int m = bi * 16 + lm;
                int o1 = m * 512 + ((s * 32 + 4 * g) ^ xsw);
                int o2 = m * 512 + ((s * 32 + 16 + 4 * g) ^ xsw);
                bh[bi] = ld_frag(hh, o1, o2);
                bl[bi] = ld_frag(hl, o1, o2);
            }
            #pragma unroll
            for (int jf = 0; jf < 4; ++jf)
                #pragma unroll
                for (int bi = 0; bi < 2; ++bi) {
                    acc[jf][bi] = __builtin_amdgcn_mfma_f32_16x16x32_bf16(ahc[jf], bh[bi], acc[jf][bi], 0, 0, 0);
                    acc[jf][bi] = __builtin_amdgcn_mfma_f32_16x16x32_bf16(ahc[jf], bl[bi], acc[jf][bi], 0, 0, 0);
                    acc[jf][bi] = __builtin_amdgcn_mfma_f32_16x16x32_bf16(alc[jf], bh[bi], acc[jf][bi], 0, 0, 0);
                }
            if (s < 15) {
                #pragma unroll
                for (int jf = 0; jf < 4; ++jf) { ahc[jf] = ahn[jf]; alc[jf] = aln[jf]; }
            }
        }

        // writes go to the OTHER buffer; next t's barrier orders them
        buf ^= 1;
        #pragma unroll
        for (int jf = 0; jf < 4; ++jf)
            #pragma unroll
            for (int bi = 0; bi < 2; ++bi) {
                f32x4 r;
                r[0] = lrelu(acc[jf][bi][0] + pregs[jf][bi][0]);
                r[1] = lrelu(acc[jf][bi][1] + pregs[jf][bi][1]);
                r[2] = lrelu(acc[jf][bi][2] + pregs[jf][bi][2]);
                r[3] = lrelu(acc[jf][bi][3] + pregs[jf][bi][3]);
                nt_store4(obase[bi] + t * HID + jf * 16, r);
                int m = bi * 16 + lm;
                int nb = w * 64 + jf * 16 + 4 * g;
                store_hilo(&hbuf[buf][0][0], &hbuf[buf][1][0], m * 512 + (nb ^ xsw), r);
            }
    }
}

// ---------------------------------------------------------------------------
extern "C" void kernel_launch(void* const* d_in, const int* in_sizes, int n_in,
                              void* d_out, int out_size, void* d_ws, size_t ws_size,
                              hipStream_t stream) {
    const float* X  = (const float*)d_in[0];  // (8192, 23, 256)
    const float* A  = (const float*)d_in[1];  // (256, 256)
    const float* Bv = (const float*)d_in[2];  // (256, 1)
    const float* Wh = (const float*)d_in[3];  // (512, 512)
    const float* Wm = (const float*)d_in[4];  // (512, 256)
    const float* Wx = (const float*)d_in[5];  // (256, 512)
    const float* ex = (const float*)d_in[6];  // (256, 1)
    float* out = (float*)d_out;               // (8192, 23, 512)

    const int nrows = NBATCH * T_STEPS;       // 188416

    // workspace layout (~2.4 MB total; round-2's 1.9 MB ran fine)
    float* u    = (float*)d_ws;                         // 188416 f
    float* V    = u + nrows;                            // 5888 f
    float* wtab = V + T_STEPS * ORD;                    // 11776 f
    ushort* whp_hi = (ushort*)(wtab + T_STEPS * HID);   // 262144 us
    ushort* whp_lo = whp_hi + HID * HID;                // 262144
    ushort* wxp_hi = whp_lo + HID * HID;                // 131072
    ushort* wxp_lo = wxp_hi + IN_DIM * HID;             // 131072
    ushort* wtp_hi = wxp_lo + IN_DIM * HID;             // 16384
    ushort* wtp_lo = wtp_hi + 32 * 512;                 // 16384

    // 1) memory-kernel taps + weight prepacks
    vchain_kernel<<<1, 256, 0, stream>>>(A, Bv, V);
    wtab_kernel<<<dim3(T_STEPS, HID / 64), 64, 0, stream>>>(Wm, V, wtab);
    wtabpack_kernel<<<32, 64, 0, stream>>>(wtab, wtp_hi, wtp_lo);
    whpack_kernel<<<dim3(HID / 16, HID / 32), 64, 0, stream>>>(Wh, whp_hi, whp_lo);
    wxpack_kernel<<<dim3(HID / 16, IN_DIM / 32), 64, 0, stream>>>(Wx, wxp_hi, wxp_lo);

    // 2) u = X @ e_x
    u_kernel<<<nrows / 4, 256, 0, stream>>>(X, ex, u);

    // 3) pre = X @ Wx + conv(u, wtab)  (replaces gemm_xwx + memconv)
    gemm_pre<<<nrows / PRB, 512, 0, stream>>>(X, u, wxp_hi, wxp_lo,
                                              wtp_hi, wtp_lo, out);

    // 4) t = 0..22 fused recurrence
    rec_fused<<<NBATCH / ROWS, 512, 0, stream>>>(whp_hi, whp_lo, out);
}